// Round 4
// baseline (282.597 us; speedup 1.0000x reference)
//
#include <hip/hip_runtime.h>

// GGNN on MI355X. N=100000, E=1000000, H=M=64, C=16.
// R3 post-mortem: k_node (116us) latency-bound at 25.6% occupancy (2 waves/SIMD:
// 72 VGPR + 64 gate AGPRs fused into one kernel). ~166us hidden in k_scatter etc.
// R4: split gather (low-VGPR, no LDS, high-occupancy) from MFMA (per-nb AGPR
// reuse, LDS 27.6->17.4KB); vectorize k_scatter x4; fuse zero/det/prep/cvtw
// into k_init.
// ws: [featb bf16 N*64 | entries int N*CAP | counts int N | cc int N |
//      s1b bf16 N*64 | s0b bf16 N*64 | wb bf16 33792 | flag]

typedef __bf16 bf16x8 __attribute__((ext_vector_type(8)));
typedef float  f32x4  __attribute__((ext_vector_type(4)));
typedef int    i32x4  __attribute__((ext_vector_type(4)));

#define MFMA16 __builtin_amdgcn_mfma_f32_16x16x32_bf16
#define NN  100000
#define EE  1000000
#define CAP 48

__device__ __forceinline__ float sigmoidf_(float x) {
    return 1.0f / (1.0f + __expf(-x));
}

// ---- fused init ----
// block 0: edge_types dtype detect (self-contained -> no flag-zero race).
// blocks [1,392): zero counts. [392,524): weights f32->bf16. [524,6774): feat cvt.
__global__ __launch_bounds__(256) void k_init(const unsigned char* __restrict__ et,
                                              const float* __restrict__ feat,
                                              const float* __restrict__ w0,
                                              const float* __restrict__ w1,
                                              const float* __restrict__ wih,
                                              const float* __restrict__ whh,
                                              const float* __restrict__ wout,
                                              __bf16* __restrict__ featb,
                                              __bf16* __restrict__ wb,
                                              int* __restrict__ counts,
                                              int* __restrict__ flag) {
    int b = blockIdx.x, tid = threadIdx.x;
    if (b == 0) {
        // flag=1 iff any nonzero byte at offset%4!=0 in first 64KB (bool storage);
        // int32 0/1 storage has bytes 1..3 of every word zero.
        __shared__ int sdet[4];
        const i32x4* p = (const i32x4*)et + tid * 16;  // 256 B per thread
        unsigned acc = 0;
#pragma unroll
        for (int j = 0; j < 16; j++) {
            i32x4 w = p[j];
            acc |= (unsigned)(w[0] | w[1] | w[2] | w[3]) & 0xffffff00u;
        }
        unsigned long long m = __ballot(acc != 0);
        if ((tid & 63) == 0) sdet[tid >> 6] = (m != 0ULL);
        __syncthreads();
        if (tid == 0) *flag = sdet[0] | sdet[1] | sdet[2] | sdet[3];
        return;
    }
    if (b < 392) {
        int i = (b - 1) * 256 + tid;
        if (i < NN) counts[i] = 0;
        return;
    }
    if (b < 524) {
        int i = (b - 392) * 256 + tid;
        float v;
        if      (i < 4096)  v = w0[i];
        else if (i < 8192)  v = w1[i - 4096];
        else if (i < 20480) v = wih[i - 8192];
        else if (i < 32768) v = whh[i - 20480];
        else if (i < 33792) v = wout[i - 32768];
        else return;
        wb[i] = (__bf16)v;
        return;
    }
    long i = ((long)(b - 524) * 256 + tid) * 4;
    if (i >= (long)NN * 64) return;
    f32x4 v = *(const f32x4*)(feat + i);
    union { __bf16 e[4]; unsigned long long u; } o;
#pragma unroll
    for (int j = 0; j < 4; j++) o.e[j] = (__bf16)v[j];
    *(unsigned long long*)(featb + i) = o.u;
}

// ---- build per-dst edge lists, 4 edges/thread ----
__global__ __launch_bounds__(256) void k_scatter(const int* __restrict__ src,
                                                 const int* __restrict__ dst,
                                                 const unsigned char* __restrict__ etype,
                                                 const int* __restrict__ flag,
                                                 int* __restrict__ counts,
                                                 int* __restrict__ entries) {
    int e0 = (blockIdx.x * 256 + threadIdx.x) * 4;
    if (e0 >= EE) return;
    i32x4 s4 = *(const i32x4*)(src + e0);
    i32x4 d4 = *(const i32x4*)(dst + e0);
    int t[4];
    if (*flag) {  // 1-byte bool storage
        unsigned w = *(const unsigned*)(etype + e0);
        t[0] = w & 0xff; t[1] = (w >> 8) & 0xff; t[2] = (w >> 16) & 0xff; t[3] = (w >> 24) & 0xff;
    } else {      // int32 storage
        i32x4 w = *(const i32x4*)((const int*)etype + e0);
        t[0] = w[0]; t[1] = w[1]; t[2] = w[2]; t[3] = w[3];
    }
#pragma unroll
    for (int j = 0; j < 4; j++) {
        int d = d4[j];
        int slot = atomicAdd(&counts[d], 1);
        if (slot < CAP) entries[d * CAP + slot] = s4[j] | (t[j] ? (1 << 31) : 0);
    }
}

// ---- gather: fp32 type-split feature sums -> bf16 S1/S0 + packed counts ----
// One wave = 16 nodes; lane (L,q) owns node n0+L's k-chunks {q*8, 32+q*8}
// (exactly the MFMA A-frag layout k_mm will load). No LDS, ~56 VGPR ->
// high occupancy for latency hiding of the dependent entry->row loads.
__global__ __launch_bounds__(256) void k_gather(const __bf16* __restrict__ featb,
                                                const int* __restrict__ counts,
                                                const int* __restrict__ entries,
                                                __bf16* __restrict__ s1b,
                                                __bf16* __restrict__ s0b,
                                                int* __restrict__ cc) {
    int tid = threadIdx.x, lane = tid & 63, wave = tid >> 6;
    int L = lane & 15, q = lane >> 4;
    int n0 = (blockIdx.x * 4 + wave) * 16;
    if (n0 >= NN) return;
    int n = n0 + L;
    int cnt = min(counts[n], CAP);
    const int* eb = entries + (long)n * CAP;
    float sA[16], s1[16];
#pragma unroll
    for (int j = 0; j < 16; j++) { sA[j] = 0.f; s1[j] = 0.f; }
    int c1 = 0;
    for (int i = 0; i < cnt; i++) {
        int ent = eb[i];
        int s = ent & 0x7fffffff;
        int t = ((unsigned)ent) >> 31;
        const __bf16* row = featb + (long)s * 64;
        bf16x8 a = *(const bf16x8*)(row + q * 8);
        bf16x8 b = *(const bf16x8*)(row + 32 + q * 8);
        c1 += t;
        float ft = (float)t;  // predicated fma instead of divergent branch
#pragma unroll
        for (int j = 0; j < 8; j++) {
            float va = (float)a[j], vb = (float)b[j];
            sA[j] += va;     sA[8 + j] += vb;
            s1[j] += ft * va; s1[8 + j] += ft * vb;
        }
    }
    union { bf16x8 v; __bf16 e[8]; } u;
#pragma unroll
    for (int ch = 0; ch < 2; ch++) {
#pragma unroll
        for (int j = 0; j < 8; j++) u.e[j] = (__bf16)s1[ch * 8 + j];
        *(bf16x8*)(s1b + (long)n * 64 + ch * 32 + q * 8) = u.v;
#pragma unroll
        for (int j = 0; j < 8; j++) u.e[j] = (__bf16)(sA[ch * 8 + j] - s1[ch * 8 + j]);
        *(bf16x8*)(s0b + (long)n * 64 + ch * 32 + q * 8) = u.v;
    }
    if (q == 0) cc[n] = cnt | (c1 << 16);  // all q-lanes computed identical cnt/c1
}

// ---- MFMA stage: agg = S1@W0^T + S0@W1^T + count-biases; GRU; classifier ----
// Per-nb accumulator reuse keeps live AGPRs ~16-20 (R3 fused kernel held 64).
__global__ __launch_bounds__(256) void k_mm(const __bf16* __restrict__ s1b,
                                            const __bf16* __restrict__ s0b,
                                            const __bf16* __restrict__ featb,
                                            const float* __restrict__ feat,
                                            const int* __restrict__ cc,
                                            const __bf16* __restrict__ wb,
                                            const float* __restrict__ b0,
                                            const float* __restrict__ b1,
                                            const float* __restrict__ bih,
                                            const float* __restrict__ bhh,
                                            const float* __restrict__ bout,
                                            float* __restrict__ out) {
    // per-wave LDS, sT (f32 [16][68]) and sH (bf16 [16][80]) union'd: sT is dead
    // once Aag is built, before the first sH write (same-wave in-order LDS ops).
    __shared__ __align__(16) char smem[4][4352];
    int tid = threadIdx.x, lane = tid & 63, wave = tid >> 6;
    int L = lane & 15, q = lane >> 4;
    int n0 = (blockIdx.x * 4 + wave) * 16;
    if (n0 >= NN) return;
    float*  sT = (float*)smem[wave];
    __bf16* sH = (__bf16*)smem[wave];

    const __bf16* r1 = s1b + (long)(n0 + L) * 64;
    const __bf16* r0 = s0b + (long)(n0 + L) * 64;
    bf16x8 AS1[2] = { *(const bf16x8*)(r1 + q * 8), *(const bf16x8*)(r1 + 32 + q * 8) };
    bf16x8 AS0[2] = { *(const bf16x8*)(r0 + q * 8), *(const bf16x8*)(r0 + 32 + q * 8) };

    float fc1[4], fc0[4];
#pragma unroll
    for (int r = 0; r < 4; r++) {
        int v = cc[n0 + q * 4 + r];
        int c1 = v >> 16, ct = v & 0xffff;
        fc1[r] = (float)c1; fc0[r] = (float)(ct - c1);
    }

    const __bf16* w0b = wb, * w1b = wb + 4096;
    const __bf16* wihb = wb + 8192, * whhb = wb + 20480, * woutb = wb + 32768;
    f32x4 zz = {0.f, 0.f, 0.f, 0.f};

#pragma unroll
    for (int nb = 0; nb < 4; nb++) {
        f32x4 acc = zz;
#pragma unroll
        for (int ch = 0; ch < 2; ch++) {
            int off = (nb * 16 + L) * 64 + ch * 32 + q * 8;
            acc = MFMA16(AS1[ch], *(const bf16x8*)(w0b + off), acc, 0, 0, 0);
            acc = MFMA16(AS0[ch], *(const bf16x8*)(w1b + off), acc, 0, 0, 0);
        }
        float bs0 = b0[nb * 16 + L], bs1 = b1[nb * 16 + L];
#pragma unroll
        for (int r = 0; r < 4; r++)
            sT[(q * 4 + r) * 68 + nb * 16 + L] = acc[r] + fc1[r] * bs0 + fc0[r] * bs1;
    }

    // D->A transpose read (sT dead after this)
    bf16x8 Aag[2], Aft[2];
#pragma unroll
    for (int ch = 0; ch < 2; ch++) {
        union { bf16x8 v; __bf16 e[8]; } u;
#pragma unroll
        for (int j = 0; j < 8; j++) u.e[j] = (__bf16)sT[L * 68 + ch * 32 + q * 8 + j];
        Aag[ch] = u.v;
    }
    const __bf16* fr = featb + (long)(n0 + L) * 64;
    Aft[0] = *(const bf16x8*)(fr + q * 8);
    Aft[1] = *(const bf16x8*)(fr + 32 + q * 8);

    // GRU gates [r,z,n]; per-nb so accumulators release before next nb
#pragma unroll
    for (int nb = 0; nb < 4; nb++) {
        f32x4 aR = zz, aZ = zz, aIN = zz, aHN = zz;
        int row = nb * 16 + L;
#pragma unroll
        for (int ch = 0; ch < 2; ch++) {
            int ko = ch * 32 + q * 8;
            aR  = MFMA16(Aag[ch], *(const bf16x8*)(wihb + row * 64 + ko), aR, 0, 0, 0);
            aR  = MFMA16(Aft[ch], *(const bf16x8*)(whhb + row * 64 + ko), aR, 0, 0, 0);
            aZ  = MFMA16(Aag[ch], *(const bf16x8*)(wihb + (64 + row) * 64 + ko), aZ, 0, 0, 0);
            aZ  = MFMA16(Aft[ch], *(const bf16x8*)(whhb + (64 + row) * 64 + ko), aZ, 0, 0, 0);
            aIN = MFMA16(Aag[ch], *(const bf16x8*)(wihb + (128 + row) * 64 + ko), aIN, 0, 0, 0);
            aHN = MFMA16(Aft[ch], *(const bf16x8*)(whhb + (128 + row) * 64 + ko), aHN, 0, 0, 0);
        }
        int h = row;
        float br  = bih[h] + bhh[h];
        float bz  = bih[64 + h] + bhh[64 + h];
        float bin = bih[128 + h];
        float bhn = bhh[128 + h];
#pragma unroll
        for (int r = 0; r < 4; r++) {
            int node = n0 + q * 4 + r;
            float rv = sigmoidf_(aR[r] + br);
            float zv = sigmoidf_(aZ[r] + bz);
            float nv = tanhf(aIN[r] + bin + rv * (aHN[r] + bhn));
            float fv = feat[(long)node * 64 + h];  // fp32 blend for accuracy
            sH[(q * 4 + r) * 80 + h] = (__bf16)((1.0f - zv) * nv + zv * fv);
        }
    }

    // out = h @ W_out^T + b_out
    bf16x8 Ah0 = *(const bf16x8*)&sH[L * 80 + q * 8];
    bf16x8 Ah1 = *(const bf16x8*)&sH[L * 80 + 32 + q * 8];
    bf16x8 Bo0 = *(const bf16x8*)(woutb + L * 64 + q * 8);
    bf16x8 Bo1 = *(const bf16x8*)(woutb + L * 64 + 32 + q * 8);
    f32x4 o = zz;
    o = MFMA16(Ah0, Bo0, o, 0, 0, 0);
    o = MFMA16(Ah1, Bo1, o, 0, 0, 0);
    float bo = bout[L];
#pragma unroll
    for (int r = 0; r < 4; r++)
        out[(long)(n0 + q * 4 + r) * 16 + L] = o[r] + bo;
}

extern "C" void kernel_launch(void* const* d_in, const int* in_sizes, int n_in,
                              void* d_out, int out_size, void* d_ws, size_t ws_size,
                              hipStream_t stream) {
    const float* features = (const float*)d_in[0];
    const int*   src      = (const int*)d_in[1];
    const int*   dst      = (const int*)d_in[2];
    const unsigned char* etype = (const unsigned char*)d_in[3];
    const float* W0   = (const float*)d_in[4];
    const float* b0   = (const float*)d_in[5];
    const float* W1   = (const float*)d_in[6];
    const float* b1   = (const float*)d_in[7];
    const float* Wih  = (const float*)d_in[8];
    const float* Whh  = (const float*)d_in[9];
    const float* bih  = (const float*)d_in[10];
    const float* bhh  = (const float*)d_in[11];
    const float* Wout = (const float*)d_in[12];
    const float* bout = (const float*)d_in[13];
    float* out = (float*)d_out;

    char* ws = (char*)d_ws;
    size_t off = 0;
    __bf16* featb   = (__bf16*)(ws + off); off += (size_t)NN * 64 * 2;   // 12.8 MB
    int*    entries = (int*)(ws + off);    off += (size_t)NN * CAP * 4;  // 19.2 MB
    int*    counts  = (int*)(ws + off);    off += (size_t)NN * 4;
    int*    cc      = (int*)(ws + off);    off += (size_t)NN * 4;
    __bf16* s1b     = (__bf16*)(ws + off); off += (size_t)NN * 64 * 2;   // 12.8 MB
    __bf16* s0b     = (__bf16*)(ws + off); off += (size_t)NN * 64 * 2;   // 12.8 MB
    __bf16* wb      = (__bf16*)(ws + off); off += 33792 * 2;
    int*    flag    = (int*)(ws + off);

    k_init<<<6774, 256, 0, stream>>>(etype, features, W0, W1, Wih, Whh, Wout,
                                     featb, wb, counts, flag);
    k_scatter<<<(EE / 4 + 255) / 256, 256, 0, stream>>>(src, dst, etype, flag,
                                                        counts, entries);
    k_gather<<<1563, 256, 0, stream>>>(featb, counts, entries, s1b, s0b, cc);
    k_mm<<<1563, 256, 0, stream>>>(s1b, s0b, featb, features, cc, wb,
                                   b0, b1, bih, bhh, bout, out);
}

// Round 5
// 279.745 us; speedup vs baseline: 1.0102x; 1.0102x over previous
//
#include <hip/hip_runtime.h>

// GGNN on MI355X. N=100000, E=1000000, H=M=64, C=16.
// R4 post-mortem: k_scatter = 85us, all pipes idle -> returning-atomic RMW
// contention: 1M slot-grabs over 400KB = ~160 RMW/cache-line. R5: pad cursors
// to one per 64B line (stride 16) -> ~10 RMW/line; unroll k_gather by 2 for
// 2x MLP on the dependent entry->row chain.
// ws: [featb bf16 N*64 | entries int N*CAP | countsP int N*16 (line-padded) |
//      cc int N | s1b bf16 N*64 | s0b bf16 N*64 | wb bf16 33792 | flag]

typedef __bf16 bf16x8 __attribute__((ext_vector_type(8)));
typedef float  f32x4  __attribute__((ext_vector_type(4)));
typedef int    i32x4  __attribute__((ext_vector_type(4)));

#define MFMA16 __builtin_amdgcn_mfma_f32_16x16x32_bf16
#define NN  100000
#define EE  1000000
#define CAP 48
#define CSTR 16  // counts stride (ints): one counter per 64B line

__device__ __forceinline__ float sigmoidf_(float x) {
    return 1.0f / (1.0f + __expf(-x));
}

// ---- fused init ----
// block 0: edge_types dtype detect. [1,1564): zero padded counts (16B/thread).
// [1564,1696): weights f32->bf16. [1696,7946): features f32->bf16.
__global__ __launch_bounds__(256) void k_init(const unsigned char* __restrict__ et,
                                              const float* __restrict__ feat,
                                              const float* __restrict__ w0,
                                              const float* __restrict__ w1,
                                              const float* __restrict__ wih,
                                              const float* __restrict__ whh,
                                              const float* __restrict__ wout,
                                              __bf16* __restrict__ featb,
                                              __bf16* __restrict__ wb,
                                              int* __restrict__ countsP,
                                              int* __restrict__ flag) {
    int b = blockIdx.x, tid = threadIdx.x;
    if (b == 0) {
        // flag=1 iff any nonzero byte at offset%4!=0 in first 64KB (bool
        // storage); int32 0/1 storage has bytes 1..3 of every word zero.
        __shared__ int sdet[4];
        const i32x4* p = (const i32x4*)et + tid * 16;  // 256 B per thread
        unsigned acc = 0;
#pragma unroll
        for (int j = 0; j < 16; j++) {
            i32x4 w = p[j];
            acc |= (unsigned)(w[0] | w[1] | w[2] | w[3]) & 0xffffff00u;
        }
        unsigned long long m = __ballot(acc != 0);
        if ((tid & 63) == 0) sdet[tid >> 6] = (m != 0ULL);
        __syncthreads();
        if (tid == 0) *flag = sdet[0] | sdet[1] | sdet[2] | sdet[3];
        return;
    }
    if (b < 1564) {
        long i = ((long)(b - 1) * 256 + tid) * 4;
        if (i < (long)NN * CSTR) {
            i32x4 z = {0, 0, 0, 0};
            *(i32x4*)(countsP + i) = z;
        }
        return;
    }
    if (b < 1696) {
        int i = (b - 1564) * 256 + tid;
        float v;
        if      (i < 4096)  v = w0[i];
        else if (i < 8192)  v = w1[i - 4096];
        else if (i < 20480) v = wih[i - 8192];
        else if (i < 32768) v = whh[i - 20480];
        else if (i < 33792) v = wout[i - 32768];
        else return;
        wb[i] = (__bf16)v;
        return;
    }
    long i = ((long)(b - 1696) * 256 + tid) * 4;
    if (i >= (long)NN * 64) return;
    f32x4 v = *(const f32x4*)(feat + i);
    union { __bf16 e[4]; unsigned long long u; } o;
#pragma unroll
    for (int j = 0; j < 4; j++) o.e[j] = (__bf16)v[j];
    *(unsigned long long*)(featb + i) = o.u;
}

// ---- build per-dst edge lists, 4 edges/thread; line-exclusive cursors ----
__global__ __launch_bounds__(256) void k_scatter(const int* __restrict__ src,
                                                 const int* __restrict__ dst,
                                                 const unsigned char* __restrict__ etype,
                                                 const int* __restrict__ flag,
                                                 int* __restrict__ countsP,
                                                 int* __restrict__ entries) {
    int e0 = (blockIdx.x * 256 + threadIdx.x) * 4;
    if (e0 >= EE) return;
    i32x4 s4 = *(const i32x4*)(src + e0);
    i32x4 d4 = *(const i32x4*)(dst + e0);
    int t[4];
    if (*flag) {  // 1-byte bool storage
        unsigned w = *(const unsigned*)(etype + e0);
        t[0] = w & 0xff; t[1] = (w >> 8) & 0xff; t[2] = (w >> 16) & 0xff; t[3] = (w >> 24) & 0xff;
    } else {      // int32 storage
        i32x4 w = *(const i32x4*)((const int*)etype + e0);
        t[0] = w[0]; t[1] = w[1]; t[2] = w[2]; t[3] = w[3];
    }
#pragma unroll
    for (int j = 0; j < 4; j++) {
        int d = d4[j];
        int slot = atomicAdd(&countsP[d * CSTR], 1);
        if (slot < CAP) entries[d * CAP + slot] = s4[j] | (t[j] ? (1 << 31) : 0);
    }
}

// ---- gather: fp32 type-split feature sums -> bf16 S1/S0 + packed counts ----
// One wave = 16 nodes; lane (L,q) owns node n0+L's k-chunks {q*8, 32+q*8}
// (the MFMA A-frag layout k_mm loads). Unrolled x2: both entries and both
// rows issued before accumulation -> 2x MLP on the latency chain.
__global__ __launch_bounds__(256) void k_gather(const __bf16* __restrict__ featb,
                                                const int* __restrict__ countsP,
                                                const int* __restrict__ entries,
                                                __bf16* __restrict__ s1b,
                                                __bf16* __restrict__ s0b,
                                                int* __restrict__ cc) {
    int tid = threadIdx.x, lane = tid & 63, wave = tid >> 6;
    int L = lane & 15, q = lane >> 4;
    int n0 = (blockIdx.x * 4 + wave) * 16;
    if (n0 >= NN) return;
    int n = n0 + L;
    int cnt = min(countsP[n * CSTR], CAP);
    const int* eb = entries + (long)n * CAP;
    float sA[16], s1[16];
#pragma unroll
    for (int j = 0; j < 16; j++) { sA[j] = 0.f; s1[j] = 0.f; }
    int c1 = 0;
    int i = 0;
    for (; i + 2 <= cnt; i += 2) {
        int ea = eb[i], ebn = eb[i + 1];
        const __bf16* rowa = featb + (long)(ea & 0x7fffffff) * 64;
        const __bf16* rowb = featb + (long)(ebn & 0x7fffffff) * 64;
        bf16x8 a0 = *(const bf16x8*)(rowa + q * 8);
        bf16x8 a1 = *(const bf16x8*)(rowa + 32 + q * 8);
        bf16x8 b0v = *(const bf16x8*)(rowb + q * 8);
        bf16x8 b1v = *(const bf16x8*)(rowb + 32 + q * 8);
        int ta = ((unsigned)ea) >> 31, tb = ((unsigned)ebn) >> 31;
        c1 += ta + tb;
        float fa = (float)ta, fb = (float)tb;
#pragma unroll
        for (int j = 0; j < 8; j++) {
            float va = (float)a0[j], wa = (float)a1[j];
            float vb = (float)b0v[j], wb2 = (float)b1v[j];
            sA[j]     += va + vb;
            sA[8 + j] += wa + wb2;
            s1[j]     += fa * va + fb * vb;
            s1[8 + j] += fa * wa + fb * wb2;
        }
    }
    if (i < cnt) {
        int ea = eb[i];
        const __bf16* rowa = featb + (long)(ea & 0x7fffffff) * 64;
        bf16x8 a0 = *(const bf16x8*)(rowa + q * 8);
        bf16x8 a1 = *(const bf16x8*)(rowa + 32 + q * 8);
        int ta = ((unsigned)ea) >> 31;
        c1 += ta;
        float fa = (float)ta;
#pragma unroll
        for (int j = 0; j < 8; j++) {
            float va = (float)a0[j], wa = (float)a1[j];
            sA[j] += va;          sA[8 + j] += wa;
            s1[j] += fa * va;     s1[8 + j] += fa * wa;
        }
    }
    union { bf16x8 v; __bf16 e[8]; } u;
#pragma unroll
    for (int ch = 0; ch < 2; ch++) {
#pragma unroll
        for (int j = 0; j < 8; j++) u.e[j] = (__bf16)s1[ch * 8 + j];
        *(bf16x8*)(s1b + (long)n * 64 + ch * 32 + q * 8) = u.v;
#pragma unroll
        for (int j = 0; j < 8; j++) u.e[j] = (__bf16)(sA[ch * 8 + j] - s1[ch * 8 + j]);
        *(bf16x8*)(s0b + (long)n * 64 + ch * 32 + q * 8) = u.v;
    }
    if (q == 0) cc[n] = cnt | (c1 << 16);  // all q-lanes computed identical cnt/c1
}

// ---- MFMA stage: agg = S1@W0^T + S0@W1^T + count-biases; GRU; classifier ----
__global__ __launch_bounds__(256) void k_mm(const __bf16* __restrict__ s1b,
                                            const __bf16* __restrict__ s0b,
                                            const __bf16* __restrict__ featb,
                                            const float* __restrict__ feat,
                                            const int* __restrict__ cc,
                                            const __bf16* __restrict__ wb,
                                            const float* __restrict__ b0,
                                            const float* __restrict__ b1,
                                            const float* __restrict__ bih,
                                            const float* __restrict__ bhh,
                                            const float* __restrict__ bout,
                                            float* __restrict__ out) {
    // per-wave LDS; sT (f32 [16][68]) and sH (bf16 [16][80]) union'd: sT dead
    // once Aag is built, before the first sH write (same-wave in-order LDS).
    __shared__ __align__(16) char smem[4][4352];
    int tid = threadIdx.x, lane = tid & 63, wave = tid >> 6;
    int L = lane & 15, q = lane >> 4;
    int n0 = (blockIdx.x * 4 + wave) * 16;
    if (n0 >= NN) return;
    float*  sT = (float*)smem[wave];
    __bf16* sH = (__bf16*)smem[wave];

    const __bf16* r1 = s1b + (long)(n0 + L) * 64;
    const __bf16* r0 = s0b + (long)(n0 + L) * 64;
    bf16x8 AS1[2] = { *(const bf16x8*)(r1 + q * 8), *(const bf16x8*)(r1 + 32 + q * 8) };
    bf16x8 AS0[2] = { *(const bf16x8*)(r0 + q * 8), *(const bf16x8*)(r0 + 32 + q * 8) };

    float fc1[4], fc0[4];
#pragma unroll
    for (int r = 0; r < 4; r++) {
        int v = cc[n0 + q * 4 + r];
        int c1 = v >> 16, ct = v & 0xffff;
        fc1[r] = (float)c1; fc0[r] = (float)(ct - c1);
    }

    const __bf16* w0b = wb, * w1b = wb + 4096;
    const __bf16* wihb = wb + 8192, * whhb = wb + 20480, * woutb = wb + 32768;
    f32x4 zz = {0.f, 0.f, 0.f, 0.f};

#pragma unroll
    for (int nb = 0; nb < 4; nb++) {
        f32x4 acc = zz;
#pragma unroll
        for (int ch = 0; ch < 2; ch++) {
            int off = (nb * 16 + L) * 64 + ch * 32 + q * 8;
            acc = MFMA16(AS1[ch], *(const bf16x8*)(w0b + off), acc, 0, 0, 0);
            acc = MFMA16(AS0[ch], *(const bf16x8*)(w1b + off), acc, 0, 0, 0);
        }
        float bs0 = b0[nb * 16 + L], bs1 = b1[nb * 16 + L];
#pragma unroll
        for (int r = 0; r < 4; r++)
            sT[(q * 4 + r) * 68 + nb * 16 + L] = acc[r] + fc1[r] * bs0 + fc0[r] * bs1;
    }

    // D->A transpose read (sT dead after this)
    bf16x8 Aag[2], Aft[2];
#pragma unroll
    for (int ch = 0; ch < 2; ch++) {
        union { bf16x8 v; __bf16 e[8]; } u;
#pragma unroll
        for (int j = 0; j < 8; j++) u.e[j] = (__bf16)sT[L * 68 + ch * 32 + q * 8 + j];
        Aag[ch] = u.v;
    }
    const __bf16* fr = featb + (long)(n0 + L) * 64;
    Aft[0] = *(const bf16x8*)(fr + q * 8);
    Aft[1] = *(const bf16x8*)(fr + 32 + q * 8);

    // GRU gates [r,z,n]; per-nb so accumulators release before next nb
#pragma unroll
    for (int nb = 0; nb < 4; nb++) {
        f32x4 aR = zz, aZ = zz, aIN = zz, aHN = zz;
        int row = nb * 16 + L;
#pragma unroll
        for (int ch = 0; ch < 2; ch++) {
            int ko = ch * 32 + q * 8;
            aR  = MFMA16(Aag[ch], *(const bf16x8*)(wihb + row * 64 + ko), aR, 0, 0, 0);
            aR  = MFMA16(Aft[ch], *(const bf16x8*)(whhb + row * 64 + ko), aR, 0, 0, 0);
            aZ  = MFMA16(Aag[ch], *(const bf16x8*)(wihb + (64 + row) * 64 + ko), aZ, 0, 0, 0);
            aZ  = MFMA16(Aft[ch], *(const bf16x8*)(whhb + (64 + row) * 64 + ko), aZ, 0, 0, 0);
            aIN = MFMA16(Aag[ch], *(const bf16x8*)(wihb + (128 + row) * 64 + ko), aIN, 0, 0, 0);
            aHN = MFMA16(Aft[ch], *(const bf16x8*)(whhb + (128 + row) * 64 + ko), aHN, 0, 0, 0);
        }
        int h = row;
        float br  = bih[h] + bhh[h];
        float bz  = bih[64 + h] + bhh[64 + h];
        float bin = bih[128 + h];
        float bhn = bhh[128 + h];
#pragma unroll
        for (int r = 0; r < 4; r++) {
            int node = n0 + q * 4 + r;
            float rv = sigmoidf_(aR[r] + br);
            float zv = sigmoidf_(aZ[r] + bz);
            float nv = tanhf(aIN[r] + bin + rv * (aHN[r] + bhn));
            float fv = feat[(long)node * 64 + h];  // fp32 blend for accuracy
            sH[(q * 4 + r) * 80 + h] = (__bf16)((1.0f - zv) * nv + zv * fv);
        }
    }

    // out = h @ W_out^T + b_out
    bf16x8 Ah0 = *(const bf16x8*)&sH[L * 80 + q * 8];
    bf16x8 Ah1 = *(const bf16x8*)&sH[L * 80 + 32 + q * 8];
    bf16x8 Bo0 = *(const bf16x8*)(woutb + L * 64 + q * 8);
    bf16x8 Bo1 = *(const bf16x8*)(woutb + L * 64 + 32 + q * 8);
    f32x4 o = zz;
    o = MFMA16(Ah0, Bo0, o, 0, 0, 0);
    o = MFMA16(Ah1, Bo1, o, 0, 0, 0);
    float bo = bout[L];
#pragma unroll
    for (int r = 0; r < 4; r++)
        out[(long)(n0 + q * 4 + r) * 16 + L] = o[r] + bo;
}

extern "C" void kernel_launch(void* const* d_in, const int* in_sizes, int n_in,
                              void* d_out, int out_size, void* d_ws, size_t ws_size,
                              hipStream_t stream) {
    const float* features = (const float*)d_in[0];
    const int*   src      = (const int*)d_in[1];
    const int*   dst      = (const int*)d_in[2];
    const unsigned char* etype = (const unsigned char*)d_in[3];
    const float* W0   = (const float*)d_in[4];
    const float* b0   = (const float*)d_in[5];
    const float* W1   = (const float*)d_in[6];
    const float* b1   = (const float*)d_in[7];
    const float* Wih  = (const float*)d_in[8];
    const float* Whh  = (const float*)d_in[9];
    const float* bih  = (const float*)d_in[10];
    const float* bhh  = (const float*)d_in[11];
    const float* Wout = (const float*)d_in[12];
    const float* bout = (const float*)d_in[13];
    float* out = (float*)d_out;

    char* ws = (char*)d_ws;
    size_t off = 0;
    __bf16* featb   = (__bf16*)(ws + off); off += (size_t)NN * 64 * 2;     // 12.8 MB
    int*    entries = (int*)(ws + off);    off += (size_t)NN * CAP * 4;    // 19.2 MB
    int*    countsP = (int*)(ws + off);    off += (size_t)NN * CSTR * 4;   // 6.4 MB
    int*    cc      = (int*)(ws + off);    off += (size_t)NN * 4;
    __bf16* s1b     = (__bf16*)(ws + off); off += (size_t)NN * 64 * 2;     // 12.8 MB
    __bf16* s0b     = (__bf16*)(ws + off); off += (size_t)NN * 64 * 2;     // 12.8 MB
    __bf16* wb      = (__bf16*)(ws + off); off += 33792 * 2;
    int*    flag    = (int*)(ws + off);

    k_init<<<7946, 256, 0, stream>>>(etype, features, W0, W1, Wih, Whh, Wout,
                                     featb, wb, countsP, flag);
    k_scatter<<<(EE / 4 + 255) / 256, 256, 0, stream>>>(src, dst, etype, flag,
                                                        countsP, entries);
    k_gather<<<1563, 256, 0, stream>>>(featb, countsP, entries, s1b, s0b, cc);
    k_mm<<<1563, 256, 0, stream>>>(s1b, s0b, featb, features, cc, wb,
                                   b0, b1, bih, bhh, bout, out);
}

// Round 6
// 211.733 us; speedup vs baseline: 1.3347x; 1.3212x over previous
//
#include <hip/hip_runtime.h>

// GGNN on MI355X. N=100000, E=1000000, H=M=64, C=16.
// R5 post-mortem: cursor line-padding changed nothing -> returning global
// atomics are capped ~12G/s (64 RMW round-trips per wave instr). R6: remove
// them entirely via deterministic bucket sort:
//   k_s1: per-block LDS histogram over 782 dst-buckets (128 nodes each)
//   k_s2: per-bucket wave-scan of block counts -> blockBase, bucketCnt
//         (bucket regions fixed-capacity 1600 -> static bases, no global scan)
//   k_s3: replay edges, rank via LDS cursor seeded with blockBase, write
//         packed rec (nodeLocal<<18 | type<<17 | src) into bucket region
//   k_g : per-bucket CSR build in LDS + 8-wave gather (occupancy 38%->~75%)
//   k_mm: unchanged MFMA GRU+head
// ws: [featb | region 782*1600 | hist 245*782 | blockBase 245*782 |
//      bucketCnt 782 | cc N | s1b | s0b | wb | flag]

typedef __bf16 bf16x8 __attribute__((ext_vector_type(8)));
typedef float  f32x4  __attribute__((ext_vector_type(4)));
typedef int    i32x4  __attribute__((ext_vector_type(4)));

#define MFMA16 __builtin_amdgcn_mfma_f32_16x16x32_bf16
#define NN   100000
#define EE   1000000
#define BB   782     // buckets (dst >> 7)
#define NPB  128     // nodes per bucket
#define ECAP 1600    // bucket region capacity (mean 1280, +9 sigma)
#define DCAP 48      // per-node degree cap (Poisson(10), P(>=48) ~ 1e-17)
#define CSTRD 49     // CSR LDS stride (conflict pad)
#define NB   245     // histogram blocks (4096 edges each)

__device__ __forceinline__ float sigmoidf_(float x) {
    return 1.0f / (1.0f + __expf(-x));
}

// ---- fused init: dtype detect / weight cvt / feature cvt ----
__global__ __launch_bounds__(256) void k_init(const unsigned char* __restrict__ et,
                                              const float* __restrict__ feat,
                                              const float* __restrict__ w0,
                                              const float* __restrict__ w1,
                                              const float* __restrict__ wih,
                                              const float* __restrict__ whh,
                                              const float* __restrict__ wout,
                                              __bf16* __restrict__ featb,
                                              __bf16* __restrict__ wb,
                                              int* __restrict__ flag) {
    int b = blockIdx.x, tid = threadIdx.x;
    if (b == 0) {
        // flag=1 iff any nonzero byte at offset%4!=0 in first 64KB (bool
        // storage); int32 0/1 storage has bytes 1..3 of every word zero.
        __shared__ int sdet[4];
        const i32x4* p = (const i32x4*)et + tid * 16;  // 256 B per thread
        unsigned acc = 0;
#pragma unroll
        for (int j = 0; j < 16; j++) {
            i32x4 w = p[j];
            acc |= (unsigned)(w[0] | w[1] | w[2] | w[3]) & 0xffffff00u;
        }
        unsigned long long m = __ballot(acc != 0);
        if ((tid & 63) == 0) sdet[tid >> 6] = (m != 0ULL);
        __syncthreads();
        if (tid == 0) *flag = sdet[0] | sdet[1] | sdet[2] | sdet[3];
        return;
    }
    if (b < 133) {  // 132 blocks * 256 = 33792 weights exactly
        int i = (b - 1) * 256 + tid;
        float v;
        if      (i < 4096)  v = w0[i];
        else if (i < 8192)  v = w1[i - 4096];
        else if (i < 20480) v = wih[i - 8192];
        else if (i < 32768) v = whh[i - 20480];
        else                v = wout[i - 32768];
        wb[i] = (__bf16)v;
        return;
    }
    long i = ((long)(b - 133) * 256 + tid) * 4;
    if (i >= (long)NN * 64) return;
    f32x4 v = *(const f32x4*)(feat + i);
    union { __bf16 e[4]; unsigned long long u; } o;
#pragma unroll
    for (int j = 0; j < 4; j++) o.e[j] = (__bf16)v[j];
    *(unsigned long long*)(featb + i) = o.u;
}

// ---- s1: per-block bucket histogram (LDS non-returning atomics only) ----
__global__ __launch_bounds__(512) void k_s1(const int* __restrict__ dst,
                                            int* __restrict__ hist) {
    __shared__ int cnt[BB];
    int blk = blockIdx.x, tid = threadIdx.x;
    for (int i = tid; i < BB; i += 512) cnt[i] = 0;
    __syncthreads();
    long e0 = (long)blk * 4096 + tid * 8;  // EE % 8 == 0: no scalar tail
    if (e0 < EE) {
        i32x4 d0 = *(const i32x4*)(dst + e0);
        i32x4 d1 = *(const i32x4*)(dst + e0 + 4);
#pragma unroll
        for (int j = 0; j < 4; j++) atomicAdd(&cnt[d0[j] >> 7], 1);
#pragma unroll
        for (int j = 0; j < 4; j++) atomicAdd(&cnt[d1[j] >> 7], 1);
    }
    __syncthreads();
    for (int i = tid; i < BB; i += 512) hist[blk * BB + i] = cnt[i];
}

// ---- s2: exclusive scan over blocks per bucket (1 wave/bucket) ----
__global__ __launch_bounds__(256) void k_s2(const int* __restrict__ hist,
                                            int* __restrict__ blockBase,
                                            int* __restrict__ bucketCnt) {
    int b = blockIdx.x * 4 + (threadIdx.x >> 6);
    int lane = threadIdx.x & 63;
    if (b >= BB) return;
    int carry = 0;
    for (int c = 0; c < 4; c++) {       // ceil(245/64) = 4 chunks
        int blk = c * 64 + lane;
        int v = (blk < NB) ? hist[blk * BB + b] : 0;
        int x = v;
#pragma unroll
        for (int off = 1; off < 64; off <<= 1) {
            int y = __shfl_up(x, off, 64);
            if (lane >= off) x += y;
        }
        if (blk < NB) blockBase[blk * BB + b] = x - v + carry;
        carry += __shfl(x, 63, 64);
    }
    if (lane == 0) bucketCnt[b] = carry;
}

// ---- s3: place edges deterministically (LDS cursors seeded w/ blockBase) ----
__global__ __launch_bounds__(512) void k_s3(const int* __restrict__ src,
                                            const int* __restrict__ dst,
                                            const unsigned char* __restrict__ etype,
                                            const int* __restrict__ flag,
                                            const int* __restrict__ blockBase,
                                            int* __restrict__ region) {
    __shared__ int cur[BB];
    int blk = blockIdx.x, tid = threadIdx.x;
    for (int i = tid; i < BB; i += 512) cur[i] = blockBase[blk * BB + i];
    __syncthreads();
    long e0 = (long)blk * 4096 + tid * 8;
    if (e0 >= EE) return;
    i32x4 s0 = *(const i32x4*)(src + e0);
    i32x4 s1 = *(const i32x4*)(src + e0 + 4);
    i32x4 d0 = *(const i32x4*)(dst + e0);
    i32x4 d1 = *(const i32x4*)(dst + e0 + 4);
    int t[8];
    if (*flag) {  // 1-byte bool storage
        unsigned long long w = *(const unsigned long long*)(etype + e0);
#pragma unroll
        for (int j = 0; j < 8; j++) t[j] = (int)((w >> (8 * j)) & 0xff);
    } else {      // int32 storage
        i32x4 w0 = *(const i32x4*)((const int*)etype + e0);
        i32x4 w1 = *(const i32x4*)((const int*)etype + e0 + 4);
#pragma unroll
        for (int j = 0; j < 4; j++) { t[j] = w0[j]; t[4 + j] = w1[j]; }
    }
    int dd[8] = {d0[0], d0[1], d0[2], d0[3], d1[0], d1[1], d1[2], d1[3]};
    int ss[8] = {s0[0], s0[1], s0[2], s0[3], s1[0], s1[1], s1[2], s1[3]};
#pragma unroll
    for (int j = 0; j < 8; j++) {
        int b  = dd[j] >> 7;
        int nl = dd[j] & 127;
        int r  = atomicAdd(&cur[b], 1);  // LDS returning atomic: fast
        if (r < ECAP)
            region[b * ECAP + r] = (nl << 18) | ((t[j] ? 1 : 0) << 17) | ss[j];
    }
}

// ---- gather: per-bucket CSR build in LDS, then 8 waves x 16 nodes ----
__global__ __launch_bounds__(512) void k_g(const __bf16* __restrict__ featb,
                                           const int* __restrict__ region,
                                           const int* __restrict__ bucketCnt,
                                           __bf16* __restrict__ s1b,
                                           __bf16* __restrict__ s0b,
                                           int* __restrict__ cc) {
    __shared__ int ncnt[NPB];
    __shared__ int csr[NPB * CSTRD];  // stride 49: breaks 2-bank aliasing
    int b = blockIdx.x, tid = threadIdx.x;
    int cntE = min(bucketCnt[b], ECAP);
    if (tid < NPB) ncnt[tid] = 0;
    __syncthreads();
    const int* reg = region + b * ECAP;
    for (int i = tid; i < cntE; i += 512) {
        int rec = reg[i];
        int nl = rec >> 18;
        int r = atomicAdd(&ncnt[nl], 1);
        if (r < DCAP) csr[nl * CSTRD + r] = rec & 0x3ffff;  // type|src
    }
    __syncthreads();

    int lane = tid & 63, wave = tid >> 6;
    int L = lane & 15, q = lane >> 4;
    int nl = wave * 16 + L;        // 8 waves x 16 nodes = 128
    int n = b * NPB + nl;
    int cnt = (n < NN) ? min(ncnt[nl], DCAP) : 0;
    const int* eb = &csr[nl * CSTRD];

    float sA[16], s1[16];
#pragma unroll
    for (int j = 0; j < 16; j++) { sA[j] = 0.f; s1[j] = 0.f; }
    int c1 = 0;
    int i = 0;
    for (; i + 2 <= cnt; i += 2) {  // unroll x2: 2x MLP on the latency chain
        int ea = eb[i], ebn = eb[i + 1];
        const __bf16* rowa = featb + (long)(ea & 0x1ffff) * 64;
        const __bf16* rowb = featb + (long)(ebn & 0x1ffff) * 64;
        bf16x8 a0 = *(const bf16x8*)(rowa + q * 8);
        bf16x8 a1 = *(const bf16x8*)(rowa + 32 + q * 8);
        bf16x8 b0v = *(const bf16x8*)(rowb + q * 8);
        bf16x8 b1v = *(const bf16x8*)(rowb + 32 + q * 8);
        int ta = (ea >> 17) & 1, tb = (ebn >> 17) & 1;
        c1 += ta + tb;
        float fa = (float)ta, fb = (float)tb;
#pragma unroll
        for (int j = 0; j < 8; j++) {
            float va = (float)a0[j], wa = (float)a1[j];
            float vb = (float)b0v[j], wb2 = (float)b1v[j];
            sA[j]     += va + vb;
            sA[8 + j] += wa + wb2;
            s1[j]     += fa * va + fb * vb;
            s1[8 + j] += fa * wa + fb * wb2;
        }
    }
    if (i < cnt) {
        int ea = eb[i];
        const __bf16* rowa = featb + (long)(ea & 0x1ffff) * 64;
        bf16x8 a0 = *(const bf16x8*)(rowa + q * 8);
        bf16x8 a1 = *(const bf16x8*)(rowa + 32 + q * 8);
        int ta = (ea >> 17) & 1;
        c1 += ta;
        float fa = (float)ta;
#pragma unroll
        for (int j = 0; j < 8; j++) {
            float va = (float)a0[j], wa = (float)a1[j];
            sA[j] += va;          sA[8 + j] += wa;
            s1[j] += fa * va;     s1[8 + j] += fa * wa;
        }
    }
    if (n >= NN) return;
    union { bf16x8 v; __bf16 e[8]; } u;
#pragma unroll
    for (int ch = 0; ch < 2; ch++) {
#pragma unroll
        for (int j = 0; j < 8; j++) u.e[j] = (__bf16)s1[ch * 8 + j];
        *(bf16x8*)(s1b + (long)n * 64 + ch * 32 + q * 8) = u.v;
#pragma unroll
        for (int j = 0; j < 8; j++) u.e[j] = (__bf16)(sA[ch * 8 + j] - s1[ch * 8 + j]);
        *(bf16x8*)(s0b + (long)n * 64 + ch * 32 + q * 8) = u.v;
    }
    if (q == 0) cc[n] = cnt | (c1 << 16);
}

// ---- MFMA stage: agg = S1@W0^T + S0@W1^T + count-biases; GRU; classifier ----
__global__ __launch_bounds__(256) void k_mm(const __bf16* __restrict__ s1b,
                                            const __bf16* __restrict__ s0b,
                                            const __bf16* __restrict__ featb,
                                            const float* __restrict__ feat,
                                            const int* __restrict__ cc,
                                            const __bf16* __restrict__ wb,
                                            const float* __restrict__ b0,
                                            const float* __restrict__ b1,
                                            const float* __restrict__ bih,
                                            const float* __restrict__ bhh,
                                            const float* __restrict__ bout,
                                            float* __restrict__ out) {
    // per-wave LDS; sT (f32 [16][68]) and sH (bf16 [16][80]) union'd: sT dead
    // once Aag is built, before the first sH write (same-wave in-order LDS).
    __shared__ __align__(16) char smem[4][4352];
    int tid = threadIdx.x, lane = tid & 63, wave = tid >> 6;
    int L = lane & 15, q = lane >> 4;
    int n0 = (blockIdx.x * 4 + wave) * 16;
    if (n0 >= NN) return;
    float*  sT = (float*)smem[wave];
    __bf16* sH = (__bf16*)smem[wave];

    const __bf16* r1 = s1b + (long)(n0 + L) * 64;
    const __bf16* r0 = s0b + (long)(n0 + L) * 64;
    bf16x8 AS1[2] = { *(const bf16x8*)(r1 + q * 8), *(const bf16x8*)(r1 + 32 + q * 8) };
    bf16x8 AS0[2] = { *(const bf16x8*)(r0 + q * 8), *(const bf16x8*)(r0 + 32 + q * 8) };

    float fc1[4], fc0[4];
#pragma unroll
    for (int r = 0; r < 4; r++) {
        int v = cc[n0 + q * 4 + r];
        int c1 = v >> 16, ct = v & 0xffff;
        fc1[r] = (float)c1; fc0[r] = (float)(ct - c1);
    }

    const __bf16* w0b = wb, * w1b = wb + 4096;
    const __bf16* wihb = wb + 8192, * whhb = wb + 20480, * woutb = wb + 32768;
    f32x4 zz = {0.f, 0.f, 0.f, 0.f};

#pragma unroll
    for (int nb = 0; nb < 4; nb++) {
        f32x4 acc = zz;
#pragma unroll
        for (int ch = 0; ch < 2; ch++) {
            int off = (nb * 16 + L) * 64 + ch * 32 + q * 8;
            acc = MFMA16(AS1[ch], *(const bf16x8*)(w0b + off), acc, 0, 0, 0);
            acc = MFMA16(AS0[ch], *(const bf16x8*)(w1b + off), acc, 0, 0, 0);
        }
        float bs0 = b0[nb * 16 + L], bs1 = b1[nb * 16 + L];
#pragma unroll
        for (int r = 0; r < 4; r++)
            sT[(q * 4 + r) * 68 + nb * 16 + L] = acc[r] + fc1[r] * bs0 + fc0[r] * bs1;
    }

    // D->A transpose read (sT dead after this)
    bf16x8 Aag[2], Aft[2];
#pragma unroll
    for (int ch = 0; ch < 2; ch++) {
        union { bf16x8 v; __bf16 e[8]; } u;
#pragma unroll
        for (int j = 0; j < 8; j++) u.e[j] = (__bf16)sT[L * 68 + ch * 32 + q * 8 + j];
        Aag[ch] = u.v;
    }
    const __bf16* fr = featb + (long)(n0 + L) * 64;
    Aft[0] = *(const bf16x8*)(fr + q * 8);
    Aft[1] = *(const bf16x8*)(fr + 32 + q * 8);

    // GRU gates [r,z,n]; per-nb so accumulators release before next nb
#pragma unroll
    for (int nb = 0; nb < 4; nb++) {
        f32x4 aR = zz, aZ = zz, aIN = zz, aHN = zz;
        int row = nb * 16 + L;
#pragma unroll
        for (int ch = 0; ch < 2; ch++) {
            int ko = ch * 32 + q * 8;
            aR  = MFMA16(Aag[ch], *(const bf16x8*)(wihb + row * 64 + ko), aR, 0, 0, 0);
            aR  = MFMA16(Aft[ch], *(const bf16x8*)(whhb + row * 64 + ko), aR, 0, 0, 0);
            aZ  = MFMA16(Aag[ch], *(const bf16x8*)(wihb + (64 + row) * 64 + ko), aZ, 0, 0, 0);
            aZ  = MFMA16(Aft[ch], *(const bf16x8*)(whhb + (64 + row) * 64 + ko), aZ, 0, 0, 0);
            aIN = MFMA16(Aag[ch], *(const bf16x8*)(wihb + (128 + row) * 64 + ko), aIN, 0, 0, 0);
            aHN = MFMA16(Aft[ch], *(const bf16x8*)(whhb + (128 + row) * 64 + ko), aHN, 0, 0, 0);
        }
        int h = row;
        float br  = bih[h] + bhh[h];
        float bz  = bih[64 + h] + bhh[64 + h];
        float bin = bih[128 + h];
        float bhn = bhh[128 + h];
#pragma unroll
        for (int r = 0; r < 4; r++) {
            int node = n0 + q * 4 + r;
            float rv = sigmoidf_(aR[r] + br);
            float zv = sigmoidf_(aZ[r] + bz);
            float nv = tanhf(aIN[r] + bin + rv * (aHN[r] + bhn));
            float fv = feat[(long)node * 64 + h];  // fp32 blend for accuracy
            sH[(q * 4 + r) * 80 + h] = (__bf16)((1.0f - zv) * nv + zv * fv);
        }
    }

    // out = h @ W_out^T + b_out
    bf16x8 Ah0 = *(const bf16x8*)&sH[L * 80 + q * 8];
    bf16x8 Ah1 = *(const bf16x8*)&sH[L * 80 + 32 + q * 8];
    bf16x8 Bo0 = *(const bf16x8*)(woutb + L * 64 + q * 8);
    bf16x8 Bo1 = *(const bf16x8*)(woutb + L * 64 + 32 + q * 8);
    f32x4 o = zz;
    o = MFMA16(Ah0, Bo0, o, 0, 0, 0);
    o = MFMA16(Ah1, Bo1, o, 0, 0, 0);
    float bo = bout[L];
#pragma unroll
    for (int r = 0; r < 4; r++)
        out[(long)(n0 + q * 4 + r) * 16 + L] = o[r] + bo;
}

extern "C" void kernel_launch(void* const* d_in, const int* in_sizes, int n_in,
                              void* d_out, int out_size, void* d_ws, size_t ws_size,
                              hipStream_t stream) {
    const float* features = (const float*)d_in[0];
    const int*   src      = (const int*)d_in[1];
    const int*   dst      = (const int*)d_in[2];
    const unsigned char* etype = (const unsigned char*)d_in[3];
    const float* W0   = (const float*)d_in[4];
    const float* b0   = (const float*)d_in[5];
    const float* W1   = (const float*)d_in[6];
    const float* b1   = (const float*)d_in[7];
    const float* Wih  = (const float*)d_in[8];
    const float* Whh  = (const float*)d_in[9];
    const float* bih  = (const float*)d_in[10];
    const float* bhh  = (const float*)d_in[11];
    const float* Wout = (const float*)d_in[12];
    const float* bout = (const float*)d_in[13];
    float* out = (float*)d_out;

    char* ws = (char*)d_ws;
    size_t off = 0;
    __bf16* featb     = (__bf16*)(ws + off); off += (size_t)NN * 64 * 2;     // 12.8 MB
    int*    region    = (int*)(ws + off);    off += (size_t)BB * ECAP * 4;   // 5.0 MB
    int*    hist      = (int*)(ws + off);    off += (size_t)NB * BB * 4;     // 766 KB
    int*    blockBase = (int*)(ws + off);    off += (size_t)NB * BB * 4;     // 766 KB
    int*    bucketCnt = (int*)(ws + off);    off += (size_t)BB * 4;
    int*    cc        = (int*)(ws + off);    off += (size_t)NN * 4;
    __bf16* s1b       = (__bf16*)(ws + off); off += (size_t)NN * 64 * 2;     // 12.8 MB
    __bf16* s0b       = (__bf16*)(ws + off); off += (size_t)NN * 64 * 2;     // 12.8 MB
    __bf16* wb        = (__bf16*)(ws + off); off += 33792 * 2;
    int*    flag      = (int*)(ws + off);

    k_init<<<6383, 256, 0, stream>>>(etype, features, W0, W1, Wih, Whh, Wout,
                                     featb, wb, flag);
    k_s1<<<NB, 512, 0, stream>>>(dst, hist);
    k_s2<<<(BB + 3) / 4, 256, 0, stream>>>(hist, blockBase, bucketCnt);
    k_s3<<<NB, 512, 0, stream>>>(src, dst, etype, flag, blockBase, region);
    k_g<<<BB, 512, 0, stream>>>(featb, region, bucketCnt, s1b, s0b, cc);
    k_mm<<<(NN + 63) / 64, 256, 0, stream>>>(s1b, s0b, featb, features, cc, wb,
                                             b0, b1, bih, bhh, bout, out);
}